// Round 3
// baseline (557.045 us; speedup 1.0000x reference)
//
#include <hip/hip_runtime.h>
#include <hip/hip_bf16.h>

#define BDIM 1024
#define SEQ  2048
#define NB   2
#define NH   16
#define HDIM 64
#define FFDIM 4096
#define MROWS (NB*SEQ)   // 4096 token rows

typedef __attribute__((ext_vector_type(8))) short short8;
typedef __attribute__((ext_vector_type(4))) float f32x4;

static __device__ __forceinline__ unsigned short f2bf(float f) {
  union { float f; unsigned u; } v; v.f = f;
  unsigned r = v.u + 0x7fffu + ((v.u >> 16) & 1u);
  return (unsigned short)(r >> 16);
}

static __device__ __forceinline__ f32x4 splat4(float x) {
  f32x4 v; v[0] = x; v[1] = x; v[2] = x; v[3] = x; return v;
}

#define GLOAD16(gp, lp)                                                        \
  __builtin_amdgcn_global_load_lds(                                            \
      (const __attribute__((address_space(1))) void*)(gp),                     \
      (__attribute__((address_space(3))) void*)(lp), 16, 0, 0)

// ------- fused fp32 [R][C] -> bf16 [C][R] transpose-convert, all 4 weights ----
// segmented 1D grid: [0,3072) w_qkv | [3072,4096) w_proj | [4096,8192) w_fc1 |
// [8192,12288) w_fc2. 32x32 tiles, 256 threads (32x8).
__global__ void tcvt_all(const float* __restrict__ w0, const float* __restrict__ w1,
                         const float* __restrict__ w2, const float* __restrict__ w3,
                         unsigned short* __restrict__ o0, unsigned short* __restrict__ o1,
                         unsigned short* __restrict__ o2, unsigned short* __restrict__ o3) {
  const int bid = blockIdx.x;
  const float* in; unsigned short* out; int R, C, nbx, rem;
  if (bid < 3072)      { in = w0; out = o0; R = 1024; C = 3072; rem = bid;        nbx = 96;  }
  else if (bid < 4096) { in = w1; out = o1; R = 1024; C = 1024; rem = bid - 3072; nbx = 32;  }
  else if (bid < 8192) { in = w2; out = o2; R = 1024; C = 4096; rem = bid - 4096; nbx = 128; }
  else                 { in = w3; out = o3; R = 4096; C = 1024; rem = bid - 8192; nbx = 32;  }
  const int c0 = (rem % nbx) * 32, r0 = (rem / nbx) * 32;
  __shared__ float tile[32][33];
  const int tx = threadIdx.x & 31, ty = threadIdx.x >> 5;   // 32 x 8
#pragma unroll
  for (int i = 0; i < 32; i += 8)
    tile[ty + i][tx] = in[(size_t)(r0 + ty + i) * C + c0 + tx];
  __syncthreads();
#pragma unroll
  for (int i = 0; i < 32; i += 8)
    out[(size_t)(c0 + ty + i) * R + r0 + tx] = f2bf(tile[tx][ty + i]);
}

// ---------------- bf16 V-section transpose: qkv[b][s][2048+h*64+d] -> vT[b][h][d][s]
__global__ void vtr_kernel(const unsigned short* __restrict__ qkv,
                           unsigned short* __restrict__ vt) {
  __shared__ unsigned short tile[32][33];
  const int h = blockIdx.z & 15, b = blockIdx.z >> 4;
  const int s0 = blockIdx.y * 32, d0 = blockIdx.x * 32;
  const int tx = threadIdx.x & 31, ty = threadIdx.x >> 5;   // 32 x 8
  const unsigned short* src = qkv + (size_t)b * SEQ * 3072 + 2048 + h * HDIM;
#pragma unroll
  for (int i = 0; i < 32; i += 8)
    tile[ty + i][tx] = src[(size_t)(s0 + ty + i) * 3072 + d0 + tx];
  __syncthreads();
  unsigned short* dst = vt + (size_t)(b * NH + h) * HDIM * SEQ;
#pragma unroll
  for (int i = 0; i < 32; i += 8)
    dst[(size_t)(d0 + ty + i) * SEQ + s0 + tx] = tile[tx][ty + i];
}

// ---------------- LayerNorm (fp32 in) -> bf16 out, one block per row ----------
__global__ void ln_kernel(const float* __restrict__ x, const float* __restrict__ g,
                          const float* __restrict__ b, unsigned short* __restrict__ out) {
  const int row = blockIdx.x;
  const int tid = threadIdx.x;            // 256 threads, 4 floats each
  const float4 v = ((const float4*)(x + (size_t)row * BDIM))[tid];
  float s  = v.x + v.y + v.z + v.w;
  float ss = v.x * v.x + v.y * v.y + v.z * v.z + v.w * v.w;
#pragma unroll
  for (int off = 32; off; off >>= 1) { s += __shfl_xor(s, off); ss += __shfl_xor(ss, off); }
  __shared__ float red[8];
  const int wave = tid >> 6;
  if ((tid & 63) == 0) { red[wave * 2] = s; red[wave * 2 + 1] = ss; }
  __syncthreads();
  s  = red[0] + red[2] + red[4] + red[6];
  ss = red[1] + red[3] + red[5] + red[7];
  const float mean = s * (1.0f / BDIM);
  const float inv  = rsqrtf(ss * (1.0f / BDIM) - mean * mean + 1e-5f);
  const float4 gg = ((const float4*)g)[tid];
  const float4 bb = ((const float4*)b)[tid];
  ushort4 o;
  o.x = f2bf((v.x - mean) * inv * gg.x + bb.x);
  o.y = f2bf((v.y - mean) * inv * gg.y + bb.y);
  o.z = f2bf((v.z - mean) * inv * gg.z + bb.z);
  o.w = f2bf((v.w - mean) * inv * gg.w + bb.w);
  ((ushort4*)(out + (size_t)row * BDIM))[tid] = o;
}

// ---------------- GEMM: C[M,N] = A[M,K] @ Bt[N,K]^T + bias (+epilogue) --------
// EPI 0: store bf16.  EPI 1: fp32 out = acc + bias + resid.  EPI 2: GELU -> bf16.
template <int EPI>
__global__ __launch_bounds__(256, 2)
void gemm_bt(const unsigned short* __restrict__ A, const unsigned short* __restrict__ Bt,
             const float* __restrict__ bias, const float* __restrict__ resid,
             void* __restrict__ outp, int M, int N, int K) {
  __shared__ unsigned short As[128 * 32];   // 8 KB
  __shared__ unsigned short Bs[128 * 32];   // 8 KB
  const int tid = threadIdx.x;
  const int n0 = blockIdx.x * 128, m0 = blockIdx.y * 128;
  const int lane = tid & 63, wave = tid >> 6;
  const int lr = lane & 15, lg = lane >> 4;
  const int wr = (wave >> 1) * 64, wc = (wave & 1) * 64;

  // staging: chunk j covers rows [j*64, j*64+64), lane pattern row=(e>>2), k=(e&3)*8
  const unsigned short* ga0 = A  + (size_t)(m0 + (tid >> 2)) * K + (tid & 3) * 8;
  const unsigned short* ga1 = ga0 + (size_t)64 * K;
  const unsigned short* gb0 = Bt + (size_t)(n0 + (tid >> 2)) * K + (tid & 3) * 8;
  const unsigned short* gb1 = gb0 + (size_t)64 * K;
  unsigned short* la0 = As + tid * 8;
  unsigned short* la1 = As + (256 + tid) * 8;
  unsigned short* lb0 = Bs + tid * 8;
  unsigned short* lb1 = Bs + (256 + tid) * 8;

  f32x4 acc[4][4];
#pragma unroll
  for (int i = 0; i < 4; i++)
#pragma unroll
    for (int j = 0; j < 4; j++) acc[i][j] = splat4(0.0f);

  for (int k0 = 0; k0 < K; k0 += 32) {
    GLOAD16(ga0 + k0, la0);
    GLOAD16(ga1 + k0, la1);
    GLOAD16(gb0 + k0, lb0);
    GLOAD16(gb1 + k0, lb1);
    __syncthreads();
    short8 af[4], bfr[4];
#pragma unroll
    for (int mi = 0; mi < 4; mi++)
      af[mi] = *(const short8*)(As + (wr + mi * 16 + lr) * 32 + lg * 8);
#pragma unroll
    for (int ni = 0; ni < 4; ni++)
      bfr[ni] = *(const short8*)(Bs + (wc + ni * 16 + lr) * 32 + lg * 8);
#pragma unroll
    for (int mi = 0; mi < 4; mi++)
#pragma unroll
      for (int ni = 0; ni < 4; ni++)
        acc[mi][ni] = __builtin_amdgcn_mfma_f32_16x16x32_bf16(af[mi], bfr[ni], acc[mi][ni], 0, 0, 0);
    __syncthreads();
  }

  // epilogue — bias depends only on ni; hoist the 4 loads
  float bv[4];
#pragma unroll
  for (int ni = 0; ni < 4; ni++) bv[ni] = bias[n0 + wc + ni * 16 + lr];
#pragma unroll
  for (int mi = 0; mi < 4; mi++) {
#pragma unroll
    for (int ni = 0; ni < 4; ni++) {
      const int row0 = m0 + wr + mi * 16 + lg * 4;
      const int col  = n0 + wc + ni * 16 + lr;
#pragma unroll
      for (int r = 0; r < 4; r++) {
        const float v = acc[mi][ni][r] + bv[ni];
        const size_t idx = (size_t)(row0 + r) * N + col;
        if constexpr (EPI == 0) {
          ((unsigned short*)outp)[idx] = f2bf(v);
        } else if constexpr (EPI == 1) {
          ((float*)outp)[idx] = v + resid[idx];
        } else {
          const float t = 0.5f * v * (1.0f + erff(v * 0.70710678118f));
          ((unsigned short*)outp)[idx] = f2bf(t);
        }
      }
    }
  }
}

// ---------------- causal flash attention ------------------------------------
// qkv: bf16 [NB*SEQ][3072], token row = [q(0..1023) | k(1024..2047) | v(2048..3071)],
// each section laid out [H][HD]. vT: bf16 [NB][NH][HD][SEQ] (pre-transposed V).
// out: bf16 [NB*SEQ][1024]. One wave per 16 q-rows; 4 independent waves; no barriers.
__global__ __launch_bounds__(256, 2)
void attn_kernel(const unsigned short* __restrict__ qkv,
                 const unsigned short* __restrict__ vT,
                 unsigned short* __restrict__ out) {
  __shared__ unsigned short pa[4][16 * 40];  // per-wave P tile [q][kv], pad 40
  const int wave = threadIdx.x >> 6, lane = threadIdx.x & 63;
  const int lr = lane & 15, lg = lane >> 4;
  const int q0 = blockIdx.x * 64 + wave * 16;
  const int h = blockIdx.y, bb = blockIdx.z;
  const size_t base = (size_t)bb * SEQ * 3072;
  unsigned short* paw = pa[wave];
  const unsigned short* vth = vT + (size_t)(bb * NH + h) * HDIM * SEQ;

  short8 qf[2];
  {
    const unsigned short* qrow = qkv + base + (size_t)(q0 + lr) * 3072 + h * HDIM;
    qf[0] = *(const short8*)(qrow + lg * 8);
    qf[1] = *(const short8*)(qrow + 32 + lg * 8);
  }
  f32x4 oacc[4];
#pragma unroll
  for (int n = 0; n < 4; n++) oacc[n] = splat4(0.0f);
  f32x4 m_i = splat4(-INFINITY);
  f32x4 l_i = splat4(0.0f);

  const int ntiles = (q0 + 47) >> 5;   // kv tiles of 32 needed for rows q0..q0+15
  const int nfull  = (q0 + 1) >> 5;    // tiles fully below the diagonal (no mask)

  for (int t = 0; t < ntiles; ++t) {
    const int kk = t * 32;
    // ---- QK^T : S[16 q][32 k] ----
    f32x4 s0 = splat4(0.0f), s1 = splat4(0.0f);
    {
      const unsigned short* kb = qkv + base + 1024 + h * HDIM;
      const unsigned short* kr0 = kb + (size_t)(kk + lr) * 3072;
      const unsigned short* kr1 = kb + (size_t)(kk + 16 + lr) * 3072;
      const short8 kf0 = *(const short8*)(kr0 + lg * 8);
      const short8 kf1 = *(const short8*)(kr0 + 32 + lg * 8);
      const short8 kf2 = *(const short8*)(kr1 + lg * 8);
      const short8 kf3 = *(const short8*)(kr1 + 32 + lg * 8);
      __builtin_amdgcn_s_setprio(1);
      s0 = __builtin_amdgcn_mfma_f32_16x16x32_bf16(qf[0], kf0, s0, 0, 0, 0);
      s0 = __builtin_amdgcn_mfma_f32_16x16x32_bf16(qf[1], kf1, s0, 0, 0, 0);
      s1 = __builtin_amdgcn_mfma_f32_16x16x32_bf16(qf[0], kf2, s1, 0, 0, 0);
      s1 = __builtin_amdgcn_mfma_f32_16x16x32_bf16(qf[1], kf3, s1, 0, 0, 0);
      __builtin_amdgcn_s_setprio(0);
    }
    // ---- online softmax (rows live in regs r, cols across 16 lanes) ----
    const bool need_mask = (t >= nfull);
    f32x4 sc0, sc1;
#pragma unroll
    for (int r = 0; r < 4; ++r) {
      float a = s0[r] * 0.125f, c = s1[r] * 0.125f;
      if (need_mask) {
        const int qi = q0 + lg * 4 + r;
        if (kk + lr > qi)      a = -INFINITY;
        if (kk + 16 + lr > qi) c = -INFINITY;
      }
      sc0[r] = a; sc1[r] = c;
    }
    f32x4 mx;
#pragma unroll
    for (int r = 0; r < 4; ++r) mx[r] = fmaxf(sc0[r], sc1[r]);
#pragma unroll
    for (int msk = 1; msk < 16; msk <<= 1)
#pragma unroll
      for (int r = 0; r < 4; ++r) mx[r] = fmaxf(mx[r], __shfl_xor(mx[r], msk));
    f32x4 mnew, corr, p0, p1, psum;
#pragma unroll
    for (int r = 0; r < 4; ++r) {
      mnew[r] = fmaxf(m_i[r], mx[r]);
      corr[r] = __expf(m_i[r] - mnew[r]);
      p0[r] = __expf(sc0[r] - mnew[r]);
      p1[r] = __expf(sc1[r] - mnew[r]);
      psum[r] = p0[r] + p1[r];
    }
#pragma unroll
    for (int msk = 1; msk < 16; msk <<= 1)
#pragma unroll
      for (int r = 0; r < 4; ++r) psum[r] += __shfl_xor(psum[r], msk);
#pragma unroll
    for (int r = 0; r < 4; ++r) { l_i[r] = l_i[r] * corr[r] + psum[r]; m_i[r] = mnew[r]; }
#pragma unroll
    for (int n = 0; n < 4; ++n)
#pragma unroll
      for (int r = 0; r < 4; ++r) oacc[n][r] *= corr[r];
    // ---- P -> LDS (C-layout -> A-layout round trip) ----
#pragma unroll
    for (int r = 0; r < 4; ++r) {
      paw[(lg * 4 + r) * 40 + lr]      = f2bf(p0[r]);
      paw[(lg * 4 + r) * 40 + 16 + lr] = f2bf(p1[r]);
    }
    const short8 pf = *(const short8*)(paw + lr * 40 + lg * 8);
    // ---- PV: B-fragments straight from pre-transposed V (L2-resident) ----
    const unsigned short* vbase = vth + kk + lg * 8;
    const short8 vf0 = *(const short8*)(vbase + (size_t)(0 * 16 + lr) * SEQ);
    const short8 vf1 = *(const short8*)(vbase + (size_t)(1 * 16 + lr) * SEQ);
    const short8 vf2 = *(const short8*)(vbase + (size_t)(2 * 16 + lr) * SEQ);
    const short8 vf3 = *(const short8*)(vbase + (size_t)(3 * 16 + lr) * SEQ);
    __builtin_amdgcn_s_setprio(1);
    oacc[0] = __builtin_amdgcn_mfma_f32_16x16x32_bf16(pf, vf0, oacc[0], 0, 0, 0);
    oacc[1] = __builtin_amdgcn_mfma_f32_16x16x32_bf16(pf, vf1, oacc[1], 0, 0, 0);
    oacc[2] = __builtin_amdgcn_mfma_f32_16x16x32_bf16(pf, vf2, oacc[2], 0, 0, 0);
    oacc[3] = __builtin_amdgcn_mfma_f32_16x16x32_bf16(pf, vf3, oacc[3], 0, 0, 0);
    __builtin_amdgcn_s_setprio(0);
  }
  // ---- write O ----
  f32x4 linv;
#pragma unroll
  for (int r = 0; r < 4; ++r) linv[r] = 1.0f / l_i[r];
  unsigned short* orow = out + (size_t)(bb * SEQ + q0) * BDIM + h * HDIM;
#pragma unroll
  for (int n = 0; n < 4; ++n)
#pragma unroll
    for (int r = 0; r < 4; ++r)
      orow[(size_t)(lg * 4 + r) * BDIM + n * 16 + lr] = f2bf(oacc[n][r] * linv[r]);
}

// ---------------- launch ------------------------------------------------------
extern "C" void kernel_launch(void* const* d_in, const int* in_sizes, int n_in,
                              void* d_out, int out_size, void* d_ws, size_t ws_size,
                              hipStream_t stream) {
  const float* x      = (const float*)d_in[0];
  const float* ln1_g  = (const float*)d_in[1];
  const float* ln1_b  = (const float*)d_in[2];
  const float* w_qkv  = (const float*)d_in[3];
  const float* b_qkv  = (const float*)d_in[4];
  const float* w_proj = (const float*)d_in[5];
  const float* b_proj = (const float*)d_in[6];
  const float* ln2_g  = (const float*)d_in[7];
  const float* ln2_b  = (const float*)d_in[8];
  const float* w_fc1  = (const float*)d_in[9];
  const float* b_fc1  = (const float*)d_in[10];
  const float* w_fc2  = (const float*)d_in[11];
  const float* b_fc2  = (const float*)d_in[12];
  float* out = (float*)d_out;

  // workspace layout (bytes), 80 MB total; fc1b reuses qkv+attn region,
  // hbuf doubles as vT between the qkv GEMM and ln2.
  char* ws = (char*)d_ws;
  unsigned short* wqkvT  = (unsigned short*)(ws + 0);         //  6 MB [3072][1024]
  unsigned short* wprojT = (unsigned short*)(ws + 6291456);   //  2 MB [1024][1024]
  unsigned short* wfc1T  = (unsigned short*)(ws + 8388608);   //  8 MB [4096][1024]
  unsigned short* wfc2T  = (unsigned short*)(ws + 16777216);  //  8 MB [1024][4096]
  unsigned short* hbuf   = (unsigned short*)(ws + 25165824);  //  8 MB [4096][1024] / vT [2][16][64][2048]
  float*          x2     = (float*)         (ws + 33554432);  // 16 MB [4096][1024]
  unsigned short* qkvb   = (unsigned short*)(ws + 50331648);  // 24 MB [4096][3072]
  unsigned short* attnb  = (unsigned short*)(ws + 75497472);  //  8 MB [4096][1024]
  unsigned short* fc1b   = (unsigned short*)(ws + 50331648);  // 32 MB [4096][4096] (reuse)

  // weights -> bf16, transposed to [N][K] — one fused launch
  tcvt_all<<<12288, 256, 0, stream>>>(w_qkv, w_proj, w_fc1, w_fc2,
                                      wqkvT, wprojT, wfc1T, wfc2T);

  // attention
  ln_kernel<<<MROWS, 256, 0, stream>>>(x, ln1_g, ln1_b, hbuf);
  gemm_bt<0><<<dim3(3072 / 128, MROWS / 128), 256, 0, stream>>>(hbuf, wqkvT, b_qkv, nullptr, qkvb, MROWS, 3072, 1024);
  vtr_kernel<<<dim3(HDIM / 32, SEQ / 32, NB * NH), 256, 0, stream>>>(qkvb, hbuf);
  attn_kernel<<<dim3(SEQ / 64, NH, NB), 256, 0, stream>>>(qkvb, hbuf, attnb);
  gemm_bt<1><<<dim3(1024 / 128, MROWS / 128), 256, 0, stream>>>(attnb, wprojT, b_proj, x, x2, MROWS, 1024, 1024);

  // MLP
  ln_kernel<<<MROWS, 256, 0, stream>>>(x2, ln2_g, ln2_b, hbuf);
  gemm_bt<2><<<dim3(4096 / 128, MROWS / 128), 256, 0, stream>>>(hbuf, wfc1T, b_fc1, nullptr, fc1b, MROWS, FFDIM, 1024);
  gemm_bt<1><<<dim3(1024 / 128, MROWS / 128), 256, 0, stream>>>(fc1b, wfc2T, b_fc2, x2, out, MROWS, 1024, FFDIM);
}

// Round 4
// 443.920 us; speedup vs baseline: 1.2548x; 1.2548x over previous
//
#include <hip/hip_runtime.h>
#include <hip/hip_bf16.h>

#define BDIM 1024
#define SEQ  2048
#define NB   2
#define NH   16
#define HDIM 64
#define FFDIM 4096
#define MROWS (NB*SEQ)   // 4096 token rows

typedef __attribute__((ext_vector_type(8))) short short8;
typedef __attribute__((ext_vector_type(4))) float f32x4;

static __device__ __forceinline__ unsigned short f2bf(float f) {
  union { float f; unsigned u; } v; v.f = f;
  unsigned r = v.u + 0x7fffu + ((v.u >> 16) & 1u);
  return (unsigned short)(r >> 16);
}

static __device__ __forceinline__ f32x4 splat4(float x) {
  f32x4 v; v[0] = x; v[1] = x; v[2] = x; v[3] = x; return v;
}

#define GLOAD16(gp, lp)                                                        \
  __builtin_amdgcn_global_load_lds(                                            \
      (const __attribute__((address_space(1))) void*)(gp),                     \
      (__attribute__((address_space(3))) void*)(lp), 16, 0, 0)

// ------- fused fp32 [R][C] -> bf16 [C][R] transpose-convert, all 4 weights ----
__global__ void tcvt_all(const float* __restrict__ w0, const float* __restrict__ w1,
                         const float* __restrict__ w2, const float* __restrict__ w3,
                         unsigned short* __restrict__ o0, unsigned short* __restrict__ o1,
                         unsigned short* __restrict__ o2, unsigned short* __restrict__ o3) {
  const int bid = blockIdx.x;
  const float* in; unsigned short* out; int R, C, nbx, rem;
  if (bid < 3072)      { in = w0; out = o0; R = 1024; C = 3072; rem = bid;        nbx = 96;  }
  else if (bid < 4096) { in = w1; out = o1; R = 1024; C = 1024; rem = bid - 3072; nbx = 32;  }
  else if (bid < 8192) { in = w2; out = o2; R = 1024; C = 4096; rem = bid - 4096; nbx = 128; }
  else                 { in = w3; out = o3; R = 4096; C = 1024; rem = bid - 8192; nbx = 32;  }
  const int c0 = (rem % nbx) * 32, r0 = (rem / nbx) * 32;
  __shared__ float tile[32][33];
  const int tx = threadIdx.x & 31, ty = threadIdx.x >> 5;   // 32 x 8
#pragma unroll
  for (int i = 0; i < 32; i += 8)
    tile[ty + i][tx] = in[(size_t)(r0 + ty + i) * C + c0 + tx];
  __syncthreads();
#pragma unroll
  for (int i = 0; i < 32; i += 8)
    out[(size_t)(c0 + ty + i) * R + r0 + tx] = f2bf(tile[tx][ty + i]);
}

// ---------------- bf16 V-section transpose: qkv[b][s][2048+h*64+d] -> vT[b][h][d][s]
__global__ void vtr_kernel(const unsigned short* __restrict__ qkv,
                           unsigned short* __restrict__ vt) {
  __shared__ unsigned short tile[32][33];
  const int h = blockIdx.z & 15, b = blockIdx.z >> 4;
  const int s0 = blockIdx.y * 32, d0 = blockIdx.x * 32;
  const int tx = threadIdx.x & 31, ty = threadIdx.x >> 5;   // 32 x 8
  const unsigned short* src = qkv + (size_t)b * SEQ * 3072 + 2048 + h * HDIM;
#pragma unroll
  for (int i = 0; i < 32; i += 8)
    tile[ty + i][tx] = src[(size_t)(s0 + ty + i) * 3072 + d0 + tx];
  __syncthreads();
  unsigned short* dst = vt + (size_t)(b * NH + h) * HDIM * SEQ;
#pragma unroll
  for (int i = 0; i < 32; i += 8)
    dst[(size_t)(d0 + ty + i) * SEQ + s0 + tx] = tile[tx][ty + i];
}

// ---------------- LayerNorm (fp32 in) -> bf16 out, one block per row ----------
__global__ void ln_kernel(const float* __restrict__ x, const float* __restrict__ g,
                          const float* __restrict__ b, unsigned short* __restrict__ out) {
  const int row = blockIdx.x;
  const int tid = threadIdx.x;            // 256 threads, 4 floats each
  const float4 v = ((const float4*)(x + (size_t)row * BDIM))[tid];
  float s  = v.x + v.y + v.z + v.w;
  float ss = v.x * v.x + v.y * v.y + v.z * v.z + v.w * v.w;
#pragma unroll
  for (int off = 32; off; off >>= 1) { s += __shfl_xor(s, off); ss += __shfl_xor(ss, off); }
  __shared__ float red[8];
  const int wave = tid >> 6;
  if ((tid & 63) == 0) { red[wave * 2] = s; red[wave * 2 + 1] = ss; }
  __syncthreads();
  s  = red[0] + red[2] + red[4] + red[6];
  ss = red[1] + red[3] + red[5] + red[7];
  const float mean = s * (1.0f / BDIM);
  const float inv  = rsqrtf(ss * (1.0f / BDIM) - mean * mean + 1e-5f);
  const float4 gg = ((const float4*)g)[tid];
  const float4 bb = ((const float4*)b)[tid];
  ushort4 o;
  o.x = f2bf((v.x - mean) * inv * gg.x + bb.x);
  o.y = f2bf((v.y - mean) * inv * gg.y + bb.y);
  o.z = f2bf((v.z - mean) * inv * gg.z + bb.z);
  o.w = f2bf((v.w - mean) * inv * gg.w + bb.w);
  ((ushort4*)(out + (size_t)row * BDIM))[tid] = o;
}

// ---------------- GEMM: C[M,N] = A[M,K] @ Bt[N,K]^T + bias (+epilogue) --------
template <int EPI>
__global__ __launch_bounds__(256, 2)
void gemm_bt(const unsigned short* __restrict__ A, const unsigned short* __restrict__ Bt,
             const float* __restrict__ bias, const float* __restrict__ resid,
             void* __restrict__ outp, int M, int N, int K) {
  __shared__ unsigned short As[128 * 32];   // 8 KB
  __shared__ unsigned short Bs[128 * 32];   // 8 KB
  const int tid = threadIdx.x;
  const int n0 = blockIdx.x * 128, m0 = blockIdx.y * 128;
  const int lane = tid & 63, wave = tid >> 6;
  const int lr = lane & 15, lg = lane >> 4;
  const int wr = (wave >> 1) * 64, wc = (wave & 1) * 64;

  const unsigned short* ga0 = A  + (size_t)(m0 + (tid >> 2)) * K + (tid & 3) * 8;
  const unsigned short* ga1 = ga0 + (size_t)64 * K;
  const unsigned short* gb0 = Bt + (size_t)(n0 + (tid >> 2)) * K + (tid & 3) * 8;
  const unsigned short* gb1 = gb0 + (size_t)64 * K;
  unsigned short* la0 = As + tid * 8;
  unsigned short* la1 = As + (256 + tid) * 8;
  unsigned short* lb0 = Bs + tid * 8;
  unsigned short* lb1 = Bs + (256 + tid) * 8;

  f32x4 acc[4][4];
#pragma unroll
  for (int i = 0; i < 4; i++)
#pragma unroll
    for (int j = 0; j < 4; j++) acc[i][j] = splat4(0.0f);

  for (int k0 = 0; k0 < K; k0 += 32) {
    GLOAD16(ga0 + k0, la0);
    GLOAD16(ga1 + k0, la1);
    GLOAD16(gb0 + k0, lb0);
    GLOAD16(gb1 + k0, lb1);
    __syncthreads();
    short8 af[4], bfr[4];
#pragma unroll
    for (int mi = 0; mi < 4; mi++)
      af[mi] = *(const short8*)(As + (wr + mi * 16 + lr) * 32 + lg * 8);
#pragma unroll
    for (int ni = 0; ni < 4; ni++)
      bfr[ni] = *(const short8*)(Bs + (wc + ni * 16 + lr) * 32 + lg * 8);
#pragma unroll
    for (int mi = 0; mi < 4; mi++)
#pragma unroll
      for (int ni = 0; ni < 4; ni++)
        acc[mi][ni] = __builtin_amdgcn_mfma_f32_16x16x32_bf16(af[mi], bfr[ni], acc[mi][ni], 0, 0, 0);
    __syncthreads();
  }

  float bv[4];
#pragma unroll
  for (int ni = 0; ni < 4; ni++) bv[ni] = bias[n0 + wc + ni * 16 + lr];
#pragma unroll
  for (int mi = 0; mi < 4; mi++) {
#pragma unroll
    for (int ni = 0; ni < 4; ni++) {
      const int row0 = m0 + wr + mi * 16 + lg * 4;
      const int col  = n0 + wc + ni * 16 + lr;
#pragma unroll
      for (int r = 0; r < 4; r++) {
        const float v = acc[mi][ni][r] + bv[ni];
        const size_t idx = (size_t)(row0 + r) * N + col;
        if constexpr (EPI == 0) {
          ((unsigned short*)outp)[idx] = f2bf(v);
        } else if constexpr (EPI == 1) {
          ((float*)outp)[idx] = v + resid[idx];
        } else {
          const float t = 0.5f * v * (1.0f + erff(v * 0.70710678118f));
          ((unsigned short*)outp)[idx] = f2bf(t);
        }
      }
    }
  }
}

// ---------------- causal flash attention, v2 ---------------------------------
// 4 waves/block, QBLK=32/wave (block covers 128 q-rows), KVBLK=64/iter.
// K and V^T tiles staged in LDS once per block-iter (shared by all 4 waves),
// via global_load_lds with pre-swizzled source + XOR-swizzled reads.
__global__ __launch_bounds__(256, 3)
void attn_kernel(const unsigned short* __restrict__ qkv,
                 const unsigned short* __restrict__ vT,
                 unsigned short* __restrict__ out) {
  __shared__ unsigned short Ks[64 * 64];      // swizzled [kv][hd], 8 KB
  __shared__ unsigned short Vs[64 * 64];      // swizzled [d][kv], 8 KB
  __shared__ unsigned short Ps[4][32 * 72];   // per-wave P [q][kv], pad 72
  const int tid = threadIdx.x;
  const int wave = tid >> 6, lane = tid & 63;
  const int lr = lane & 15, lg = lane >> 4;
  const int Q0 = blockIdx.x * 128;
  const int wq0 = Q0 + wave * 32;
  const int h = blockIdx.y, bb = blockIdx.z;
  const size_t base = (size_t)bb * SEQ * 3072;
  const unsigned short* vth = vT + (size_t)(bb * NH + h) * HDIM * SEQ;
  unsigned short* psw = Ps[wave];
  const int sw = lr & 7;                      // read-side swizzle key

  // Q fragments: [qb][kc], rows wq0+qb*16+lr, k = kc*32+lg*8
  short8 qf[2][2];
#pragma unroll
  for (int qb = 0; qb < 2; ++qb)
#pragma unroll
    for (int kc = 0; kc < 2; ++kc)
      qf[qb][kc] = *(const short8*)(qkv + base +
          (size_t)(wq0 + qb * 16 + lr) * 3072 + h * HDIM + kc * 32 + lg * 8);

  f32x4 oacc[2][4];
#pragma unroll
  for (int qb = 0; qb < 2; ++qb)
#pragma unroll
    for (int n = 0; n < 4; ++n) oacc[qb][n] = splat4(0.0f);
  f32x4 m_i[2] = { splat4(-INFINITY), splat4(-INFINITY) };
  f32x4 l_i[2] = { splat4(0.0f), splat4(0.0f) };

  // staging: thread t covers row srow (32-row passes), col-block pre-swizzled
  const int srow = tid >> 3;                  // 0..31
  const int scb  = (tid & 7) ^ (srow & 7);    // source col-block (involution)
  const unsigned short* kg0 = qkv + base + (size_t)srow * 3072 + 1024 + h * HDIM + scb * 8;
  const unsigned short* vg0 = vth + (size_t)srow * SEQ + scb * 8;
  unsigned short* kl0 = Ks + tid * 8;
  unsigned short* kl1 = Ks + 2048 + tid * 8;
  unsigned short* vl0 = Vs + tid * 8;
  unsigned short* vl1 = Vs + 2048 + tid * 8;

  const int TB = Q0 / 64 + 2;                 // uniform trip count per block

  for (int t = 0; t < TB; ++t) {
    const int kk = t * 64;
    __syncthreads();                          // previous-iter LDS reads done
    GLOAD16(kg0 + (size_t)kk * 3072, kl0);
    GLOAD16(kg0 + (size_t)(kk + 32) * 3072, kl1);
    GLOAD16(vg0 + kk, vl0);
    GLOAD16(vg0 + (size_t)32 * SEQ + kk, vl1);
    __syncthreads();                          // drains vmcnt for all waves

    // ---- QK^T: S[32 q][64 kv] ----
    short8 kf[4][2];
#pragma unroll
    for (int kb = 0; kb < 4; ++kb)
#pragma unroll
      for (int kc = 0; kc < 2; ++kc)
        kf[kb][kc] = *(const short8*)(Ks + (kb * 16 + lr) * 64 +
                                      (((kc * 4 + lg) ^ sw) * 8));
    f32x4 s[2][4];
#pragma unroll
    for (int qb = 0; qb < 2; ++qb)
#pragma unroll
      for (int kb = 0; kb < 4; ++kb) s[qb][kb] = splat4(0.0f);
    __builtin_amdgcn_s_setprio(1);
#pragma unroll
    for (int qb = 0; qb < 2; ++qb)
#pragma unroll
      for (int kb = 0; kb < 4; ++kb) {
        s[qb][kb] = __builtin_amdgcn_mfma_f32_16x16x32_bf16(qf[qb][0], kf[kb][0], s[qb][kb], 0, 0, 0);
        s[qb][kb] = __builtin_amdgcn_mfma_f32_16x16x32_bf16(qf[qb][1], kf[kb][1], s[qb][kb], 0, 0, 0);
      }
    __builtin_amdgcn_s_setprio(0);

    // ---- scale + causal mask ----
    const bool nm = (kk + 64 > wq0);
#pragma unroll
    for (int qb = 0; qb < 2; ++qb)
#pragma unroll
      for (int kb = 0; kb < 4; ++kb)
#pragma unroll
        for (int r = 0; r < 4; ++r) {
          float v = s[qb][kb][r] * 0.125f;
          if (nm) {
            const int q = wq0 + qb * 16 + lg * 4 + r;
            if (kk + kb * 16 + lr > q) v = -INFINITY;
          }
          s[qb][kb][r] = v;
        }

    // ---- online softmax ----
    f32x4 mx[2];
#pragma unroll
    for (int qb = 0; qb < 2; ++qb) {
#pragma unroll
      for (int r = 0; r < 4; ++r)
        mx[qb][r] = fmaxf(fmaxf(s[qb][0][r], s[qb][1][r]),
                          fmaxf(s[qb][2][r], s[qb][3][r]));
    }
#pragma unroll
    for (int msk = 1; msk < 16; msk <<= 1)
#pragma unroll
      for (int qb = 0; qb < 2; ++qb)
#pragma unroll
        for (int r = 0; r < 4; ++r)
          mx[qb][r] = fmaxf(mx[qb][r], __shfl_xor(mx[qb][r], msk));
    f32x4 mnew[2], corr[2];
#pragma unroll
    for (int qb = 0; qb < 2; ++qb)
#pragma unroll
      for (int r = 0; r < 4; ++r) {
        mnew[qb][r] = fmaxf(m_i[qb][r], mx[qb][r]);
        corr[qb][r] = __expf(m_i[qb][r] - mnew[qb][r]);
      }
#pragma unroll
    for (int qb = 0; qb < 2; ++qb)
#pragma unroll
      for (int kb = 0; kb < 4; ++kb)
#pragma unroll
        for (int r = 0; r < 4; ++r)
          s[qb][kb][r] = __expf(s[qb][kb][r] - mnew[qb][r]);
    f32x4 ps[2];
#pragma unroll
    for (int qb = 0; qb < 2; ++qb)
#pragma unroll
      for (int r = 0; r < 4; ++r)
        ps[qb][r] = (s[qb][0][r] + s[qb][1][r]) + (s[qb][2][r] + s[qb][3][r]);
#pragma unroll
    for (int msk = 1; msk < 16; msk <<= 1)
#pragma unroll
      for (int qb = 0; qb < 2; ++qb)
#pragma unroll
        for (int r = 0; r < 4; ++r)
          ps[qb][r] += __shfl_xor(ps[qb][r], msk);
#pragma unroll
    for (int qb = 0; qb < 2; ++qb)
#pragma unroll
      for (int r = 0; r < 4; ++r) {
        l_i[qb][r] = l_i[qb][r] * corr[qb][r] + ps[qb][r];
        m_i[qb][r] = mnew[qb][r];
      }
#pragma unroll
    for (int qb = 0; qb < 2; ++qb)
#pragma unroll
      for (int n = 0; n < 4; ++n)
#pragma unroll
        for (int r = 0; r < 4; ++r) oacc[qb][n][r] *= corr[qb][r];

    // ---- P -> LDS (C-layout -> A-layout) ----
#pragma unroll
    for (int qb = 0; qb < 2; ++qb)
#pragma unroll
      for (int kb = 0; kb < 4; ++kb)
#pragma unroll
        for (int r = 0; r < 4; ++r)
          psw[(qb * 16 + lg * 4 + r) * 72 + kb * 16 + lr] = f2bf(s[qb][kb][r]);

    // ---- PV: O += P[32q][64kv] @ V^T[64kv][64d] ----
    short8 pf[2][2], vf[4][2];
#pragma unroll
    for (int qb = 0; qb < 2; ++qb)
#pragma unroll
      for (int kc = 0; kc < 2; ++kc)
        pf[qb][kc] = *(const short8*)(psw + (qb * 16 + lr) * 72 + kc * 32 + lg * 8);
#pragma unroll
    for (int n = 0; n < 4; ++n)
#pragma unroll
      for (int kc = 0; kc < 2; ++kc)
        vf[n][kc] = *(const short8*)(Vs + (n * 16 + lr) * 64 +
                                     (((kc * 4 + lg) ^ sw) * 8));
    __builtin_amdgcn_s_setprio(1);
#pragma unroll
    for (int qb = 0; qb < 2; ++qb)
#pragma unroll
      for (int n = 0; n < 4; ++n) {
        oacc[qb][n] = __builtin_amdgcn_mfma_f32_16x16x32_bf16(pf[qb][0], vf[n][0], oacc[qb][n], 0, 0, 0);
        oacc[qb][n] = __builtin_amdgcn_mfma_f32_16x16x32_bf16(pf[qb][1], vf[n][1], oacc[qb][n], 0, 0, 0);
      }
    __builtin_amdgcn_s_setprio(0);
  }

  // ---- write O ----
  f32x4 linv[2];
#pragma unroll
  for (int qb = 0; qb < 2; ++qb)
#pragma unroll
    for (int r = 0; r < 4; ++r) linv[qb][r] = 1.0f / l_i[qb][r];
#pragma unroll
  for (int qb = 0; qb < 2; ++qb)
#pragma unroll
    for (int n = 0; n < 4; ++n)
#pragma unroll
      for (int r = 0; r < 4; ++r)
        out[(size_t)(bb * SEQ + wq0 + qb * 16 + lg * 4 + r) * BDIM + h * HDIM + n * 16 + lr]
            = f2bf(oacc[qb][n][r] * linv[qb][r]);
}

// ---------------- launch ------------------------------------------------------
extern "C" void kernel_launch(void* const* d_in, const int* in_sizes, int n_in,
                              void* d_out, int out_size, void* d_ws, size_t ws_size,
                              hipStream_t stream) {
  const float* x      = (const float*)d_in[0];
  const float* ln1_g  = (const float*)d_in[1];
  const float* ln1_b  = (const float*)d_in[2];
  const float* w_qkv  = (const float*)d_in[3];
  const float* b_qkv  = (const float*)d_in[4];
  const float* w_proj = (const float*)d_in[5];
  const float* b_proj = (const float*)d_in[6];
  const float* ln2_g  = (const float*)d_in[7];
  const float* ln2_b  = (const float*)d_in[8];
  const float* w_fc1  = (const float*)d_in[9];
  const float* b_fc1  = (const float*)d_in[10];
  const float* w_fc2  = (const float*)d_in[11];
  const float* b_fc2  = (const float*)d_in[12];
  float* out = (float*)d_out;

  char* ws = (char*)d_ws;
  unsigned short* wqkvT  = (unsigned short*)(ws + 0);         //  6 MB [3072][1024]
  unsigned short* wprojT = (unsigned short*)(ws + 6291456);   //  2 MB [1024][1024]
  unsigned short* wfc1T  = (unsigned short*)(ws + 8388608);   //  8 MB [4096][1024]
  unsigned short* wfc2T  = (unsigned short*)(ws + 16777216);  //  8 MB [1024][4096]
  unsigned short* hbuf   = (unsigned short*)(ws + 25165824);  //  8 MB [4096][1024] / vT [2][16][64][2048]
  float*          x2     = (float*)         (ws + 33554432);  // 16 MB [4096][1024]
  unsigned short* qkvb   = (unsigned short*)(ws + 50331648);  // 24 MB [4096][3072]
  unsigned short* attnb  = (unsigned short*)(ws + 75497472);  //  8 MB [4096][1024]
  unsigned short* fc1b   = (unsigned short*)(ws + 50331648);  // 32 MB [4096][4096] (reuse)

  tcvt_all<<<12288, 256, 0, stream>>>(w_qkv, w_proj, w_fc1, w_fc2,
                                      wqkvT, wprojT, wfc1T, wfc2T);

  ln_kernel<<<MROWS, 256, 0, stream>>>(x, ln1_g, ln1_b, hbuf);
  gemm_bt<0><<<dim3(3072 / 128, MROWS / 128), 256, 0, stream>>>(hbuf, wqkvT, b_qkv, nullptr, qkvb, MROWS, 3072, 1024);
  vtr_kernel<<<dim3(HDIM / 32, SEQ / 32, NB * NH), 256, 0, stream>>>(qkvb, hbuf);
  attn_kernel<<<dim3(SEQ / 128, NH, NB), 256, 0, stream>>>(qkvb, hbuf, attnb);
  gemm_bt<1><<<dim3(1024 / 128, MROWS / 128), 256, 0, stream>>>(attnb, wprojT, b_proj, x, x2, MROWS, 1024, 1024);

  ln_kernel<<<MROWS, 256, 0, stream>>>(x2, ln2_g, ln2_b, hbuf);
  gemm_bt<2><<<dim3(4096 / 128, MROWS / 128), 256, 0, stream>>>(hbuf, wfc1T, b_fc1, nullptr, fc1b, MROWS, FFDIM, 1024);
  gemm_bt<1><<<dim3(1024 / 128, MROWS / 128), 256, 0, stream>>>(fc1b, wfc2T, b_fc2, x2, out, MROWS, 1024, FFDIM);
}

// Round 5
// 436.789 us; speedup vs baseline: 1.2753x; 1.0163x over previous
//
#include <hip/hip_runtime.h>
#include <hip/hip_bf16.h>

#define BDIM 1024
#define SEQ  2048
#define NB   2
#define NH   16
#define HDIM 64
#define FFDIM 4096
#define MROWS (NB*SEQ)   // 4096 token rows

typedef __attribute__((ext_vector_type(8))) short short8;
typedef __attribute__((ext_vector_type(4))) float f32x4;

static __device__ __forceinline__ unsigned short f2bf(float f) {
  union { float f; unsigned u; } v; v.f = f;
  unsigned r = v.u + 0x7fffu + ((v.u >> 16) & 1u);
  return (unsigned short)(r >> 16);
}

static __device__ __forceinline__ f32x4 splat4(float x) {
  f32x4 v; v[0] = x; v[1] = x; v[2] = x; v[3] = x; return v;
}

#define GLOAD16(gp, lp)                                                        \
  __builtin_amdgcn_global_load_lds(                                            \
      (const __attribute__((address_space(1))) void*)(gp),                     \
      (__attribute__((address_space(3))) void*)(lp), 16, 0, 0)

// ------- fused fp32 [R][C] -> bf16 [C][R] transpose-convert, all 4 weights ----
__global__ void tcvt_all(const float* __restrict__ w0, const float* __restrict__ w1,
                         const float* __restrict__ w2, const float* __restrict__ w3,
                         unsigned short* __restrict__ o0, unsigned short* __restrict__ o1,
                         unsigned short* __restrict__ o2, unsigned short* __restrict__ o3) {
  const int bid = blockIdx.x;
  const float* in; unsigned short* out; int R, C, nbx, rem;
  if (bid < 3072)      { in = w0; out = o0; R = 1024; C = 3072; rem = bid;        nbx = 96;  }
  else if (bid < 4096) { in = w1; out = o1; R = 1024; C = 1024; rem = bid - 3072; nbx = 32;  }
  else if (bid < 8192) { in = w2; out = o2; R = 1024; C = 4096; rem = bid - 4096; nbx = 128; }
  else                 { in = w3; out = o3; R = 4096; C = 1024; rem = bid - 8192; nbx = 32;  }
  const int c0 = (rem % nbx) * 32, r0 = (rem / nbx) * 32;
  __shared__ float tile[32][33];
  const int tx = threadIdx.x & 31, ty = threadIdx.x >> 5;   // 32 x 8
#pragma unroll
  for (int i = 0; i < 32; i += 8)
    tile[ty + i][tx] = in[(size_t)(r0 + ty + i) * C + c0 + tx];
  __syncthreads();
#pragma unroll
  for (int i = 0; i < 32; i += 8)
    out[(size_t)(c0 + ty + i) * R + r0 + tx] = f2bf(tile[tx][ty + i]);
}

// ---------------- bf16 V-section transpose: qkv[b][s][2048+h*64+d] -> vT[b][h][d][s]
__global__ void vtr_kernel(const unsigned short* __restrict__ qkv,
                           unsigned short* __restrict__ vt) {
  __shared__ unsigned short tile[32][33];
  const int h = blockIdx.z & 15, b = blockIdx.z >> 4;
  const int s0 = blockIdx.y * 32, d0 = blockIdx.x * 32;
  const int tx = threadIdx.x & 31, ty = threadIdx.x >> 5;   // 32 x 8
  const unsigned short* src = qkv + (size_t)b * SEQ * 3072 + 2048 + h * HDIM;
#pragma unroll
  for (int i = 0; i < 32; i += 8)
    tile[ty + i][tx] = src[(size_t)(s0 + ty + i) * 3072 + d0 + tx];
  __syncthreads();
  unsigned short* dst = vt + (size_t)(b * NH + h) * HDIM * SEQ;
#pragma unroll
  for (int i = 0; i < 32; i += 8)
    dst[(size_t)(d0 + ty + i) * SEQ + s0 + tx] = tile[tx][ty + i];
}

// ---------------- LayerNorm (fp32 in) -> bf16 out, one block per row ----------
__global__ void ln_kernel(const float* __restrict__ x, const float* __restrict__ g,
                          const float* __restrict__ b, unsigned short* __restrict__ out) {
  const int row = blockIdx.x;
  const int tid = threadIdx.x;            // 256 threads, 4 floats each
  const float4 v = ((const float4*)(x + (size_t)row * BDIM))[tid];
  float s  = v.x + v.y + v.z + v.w;
  float ss = v.x * v.x + v.y * v.y + v.z * v.z + v.w * v.w;
#pragma unroll
  for (int off = 32; off; off >>= 1) { s += __shfl_xor(s, off); ss += __shfl_xor(ss, off); }
  __shared__ float red[8];
  const int wave = tid >> 6;
  if ((tid & 63) == 0) { red[wave * 2] = s; red[wave * 2 + 1] = ss; }
  __syncthreads();
  s  = red[0] + red[2] + red[4] + red[6];
  ss = red[1] + red[3] + red[5] + red[7];
  const float mean = s * (1.0f / BDIM);
  const float inv  = rsqrtf(ss * (1.0f / BDIM) - mean * mean + 1e-5f);
  const float4 gg = ((const float4*)g)[tid];
  const float4 bb = ((const float4*)b)[tid];
  ushort4 o;
  o.x = f2bf((v.x - mean) * inv * gg.x + bb.x);
  o.y = f2bf((v.y - mean) * inv * gg.y + bb.y);
  o.z = f2bf((v.z - mean) * inv * gg.z + bb.z);
  o.w = f2bf((v.w - mean) * inv * gg.w + bb.w);
  ((ushort4*)(out + (size_t)row * BDIM))[tid] = o;
}

// ---------------- GEMM 128x128: C = A[M,K] @ Bt[N,K]^T + bias (+epilogue) -----
template <int EPI>
__global__ __launch_bounds__(256, 3)
void gemm_bt(const unsigned short* __restrict__ A, const unsigned short* __restrict__ Bt,
             const float* __restrict__ bias, const float* __restrict__ resid,
             void* __restrict__ outp, int M, int N, int K) {
  __shared__ unsigned short As[128 * 32];   // 8 KB
  __shared__ unsigned short Bs[128 * 32];   // 8 KB
  const int tid = threadIdx.x;
  const int n0 = blockIdx.x * 128, m0 = blockIdx.y * 128;
  const int lane = tid & 63, wave = tid >> 6;
  const int lr = lane & 15, lg = lane >> 4;
  const int wr = (wave >> 1) * 64, wc = (wave & 1) * 64;

  const unsigned short* ga0 = A  + (size_t)(m0 + (tid >> 2)) * K + (tid & 3) * 8;
  const unsigned short* ga1 = ga0 + (size_t)64 * K;
  const unsigned short* gb0 = Bt + (size_t)(n0 + (tid >> 2)) * K + (tid & 3) * 8;
  const unsigned short* gb1 = gb0 + (size_t)64 * K;
  unsigned short* la0 = As + tid * 8;
  unsigned short* la1 = As + (256 + tid) * 8;
  unsigned short* lb0 = Bs + tid * 8;
  unsigned short* lb1 = Bs + (256 + tid) * 8;

  f32x4 acc[4][4];
#pragma unroll
  for (int i = 0; i < 4; i++)
#pragma unroll
    for (int j = 0; j < 4; j++) acc[i][j] = splat4(0.0f);

  for (int k0 = 0; k0 < K; k0 += 32) {
    GLOAD16(ga0 + k0, la0);
    GLOAD16(ga1 + k0, la1);
    GLOAD16(gb0 + k0, lb0);
    GLOAD16(gb1 + k0, lb1);
    __syncthreads();
    short8 af[4], bfr[4];
#pragma unroll
    for (int mi = 0; mi < 4; mi++)
      af[mi] = *(const short8*)(As + (wr + mi * 16 + lr) * 32 + lg * 8);
#pragma unroll
    for (int ni = 0; ni < 4; ni++)
      bfr[ni] = *(const short8*)(Bs + (wc + ni * 16 + lr) * 32 + lg * 8);
#pragma unroll
    for (int mi = 0; mi < 4; mi++)
#pragma unroll
      for (int ni = 0; ni < 4; ni++)
        acc[mi][ni] = __builtin_amdgcn_mfma_f32_16x16x32_bf16(af[mi], bfr[ni], acc[mi][ni], 0, 0, 0);
    __syncthreads();
  }

  float bv[4];
#pragma unroll
  for (int ni = 0; ni < 4; ni++) bv[ni] = bias[n0 + wc + ni * 16 + lr];
#pragma unroll
  for (int mi = 0; mi < 4; mi++) {
#pragma unroll
    for (int ni = 0; ni < 4; ni++) {
      const int row0 = m0 + wr + mi * 16 + lg * 4;
      const int col  = n0 + wc + ni * 16 + lr;
#pragma unroll
      for (int r = 0; r < 4; r++) {
        const float v = acc[mi][ni][r] + bv[ni];
        const size_t idx = (size_t)(row0 + r) * N + col;
        if constexpr (EPI == 0) {
          ((unsigned short*)outp)[idx] = f2bf(v);
        } else if constexpr (EPI == 1) {
          ((float*)outp)[idx] = v + resid[idx];
        } else {
          const float t = 0.5f * v * (1.0f + erff(v * 0.70710678118f));
          ((unsigned short*)outp)[idx] = f2bf(t);
        }
      }
    }
  }
}

// ---------------- GEMM 128x64 (EPI1: fp32 out = acc+bias+resid) ---------------
// For N=1024 GEMMs (proj, fc2): doubles the grid to 512 blocks.
// 4 waves stacked in M: wave w covers rows [w*32, w*32+32), all 64 cols.
__global__ __launch_bounds__(256, 3)
void gemm_bt_n64(const unsigned short* __restrict__ A, const unsigned short* __restrict__ Bt,
                 const float* __restrict__ bias, const float* __restrict__ resid,
                 float* __restrict__ outp, int M, int N, int K) {
  __shared__ unsigned short As[128 * 32];   // 8 KB
  __shared__ unsigned short Bs[64 * 32];    // 4 KB
  const int tid = threadIdx.x;
  const int n0 = blockIdx.x * 64, m0 = blockIdx.y * 128;
  const int lane = tid & 63, wave = tid >> 6;
  const int lr = lane & 15, lg = lane >> 4;
  const int wr = wave * 32;

  const unsigned short* ga0 = A  + (size_t)(m0 + (tid >> 2)) * K + (tid & 3) * 8;
  const unsigned short* ga1 = ga0 + (size_t)64 * K;
  const unsigned short* gb0 = Bt + (size_t)(n0 + (tid >> 2)) * K + (tid & 3) * 8;
  unsigned short* la0 = As + tid * 8;
  unsigned short* la1 = As + (256 + tid) * 8;
  unsigned short* lb0 = Bs + tid * 8;

  f32x4 acc[2][4];
#pragma unroll
  for (int i = 0; i < 2; i++)
#pragma unroll
    for (int j = 0; j < 4; j++) acc[i][j] = splat4(0.0f);

  for (int k0 = 0; k0 < K; k0 += 32) {
    GLOAD16(ga0 + k0, la0);
    GLOAD16(ga1 + k0, la1);
    GLOAD16(gb0 + k0, lb0);
    __syncthreads();
    short8 af[2], bfr[4];
#pragma unroll
    for (int mi = 0; mi < 2; mi++)
      af[mi] = *(const short8*)(As + (wr + mi * 16 + lr) * 32 + lg * 8);
#pragma unroll
    for (int ni = 0; ni < 4; ni++)
      bfr[ni] = *(const short8*)(Bs + (ni * 16 + lr) * 32 + lg * 8);
#pragma unroll
    for (int mi = 0; mi < 2; mi++)
#pragma unroll
      for (int ni = 0; ni < 4; ni++)
        acc[mi][ni] = __builtin_amdgcn_mfma_f32_16x16x32_bf16(af[mi], bfr[ni], acc[mi][ni], 0, 0, 0);
    __syncthreads();
  }

  float bv[4];
#pragma unroll
  for (int ni = 0; ni < 4; ni++) bv[ni] = bias[n0 + ni * 16 + lr];
#pragma unroll
  for (int mi = 0; mi < 2; mi++) {
#pragma unroll
    for (int ni = 0; ni < 4; ni++) {
      const int row0 = m0 + wr + mi * 16 + lg * 4;
      const int col  = n0 + ni * 16 + lr;
#pragma unroll
      for (int r = 0; r < 4; r++) {
        const size_t idx = (size_t)(row0 + r) * N + col;
        outp[idx] = acc[mi][ni][r] + bv[ni] + resid[idx];
      }
    }
  }
}

// ---------------- causal flash attention, v3 ---------------------------------
// 4 waves/block, QBLK=16/wave (block covers 64 q-rows), KVBLK=64/iter.
// Grid 1024 blocks; K and V^T staged in LDS once per block-iter, swizzled.
// Softmax in exp2 domain (log2e folded into score scale).
__global__ __launch_bounds__(256, 4)
void attn_kernel(const unsigned short* __restrict__ qkv,
                 const unsigned short* __restrict__ vT,
                 unsigned short* __restrict__ out) {
  __shared__ unsigned short Ks[64 * 64];      // swizzled [kv][hd], 8 KB
  __shared__ unsigned short Vs[64 * 64];      // swizzled [d][kv], 8 KB
  __shared__ unsigned short Ps[4][16 * 72];   // per-wave P [q][kv], 9 KB
  const int tid = threadIdx.x;
  const int wave = tid >> 6, lane = tid & 63;
  const int lr = lane & 15, lg = lane >> 4;
  const int Q0 = blockIdx.x * 64;
  const int wq0 = Q0 + wave * 16;
  const int h = blockIdx.y, bb = blockIdx.z;
  const size_t base = (size_t)bb * SEQ * 3072;
  const unsigned short* vth = vT + (size_t)(bb * NH + h) * HDIM * SEQ;
  unsigned short* psw = Ps[wave];
  const int sw = lr & 7;                      // read-side swizzle key
  const float SC = 0.125f * 1.44269504089f;   // scale * log2(e)

  // Q fragments: rows wq0+lr, k = kc*32+lg*8
  short8 qf[2];
#pragma unroll
  for (int kc = 0; kc < 2; ++kc)
    qf[kc] = *(const short8*)(qkv + base +
        (size_t)(wq0 + lr) * 3072 + h * HDIM + kc * 32 + lg * 8);

  f32x4 oacc[4];
#pragma unroll
  for (int n = 0; n < 4; ++n) oacc[n] = splat4(0.0f);
  f32x4 m_i = splat4(-INFINITY);
  f32x4 l_i = splat4(0.0f);

  // staging: thread t covers row srow (32-row passes), col-block pre-swizzled
  const int srow = tid >> 3;                  // 0..31
  const int scb  = (tid & 7) ^ (srow & 7);    // source col-block (involution)
  const unsigned short* kg0 = qkv + base + (size_t)srow * 3072 + 1024 + h * HDIM + scb * 8;
  const unsigned short* vg0 = vth + (size_t)srow * SEQ + scb * 8;
  unsigned short* kl0 = Ks + tid * 8;
  unsigned short* kl1 = Ks + 2048 + tid * 8;
  unsigned short* vl0 = Vs + tid * 8;
  unsigned short* vl1 = Vs + 2048 + tid * 8;

  const int TB = blockIdx.x + 1;              // uniform trip count per block

  for (int t = 0; t < TB; ++t) {
    const int kk = t * 64;
    __syncthreads();                          // previous-iter LDS reads done
    GLOAD16(kg0 + (size_t)kk * 3072, kl0);
    GLOAD16(kg0 + (size_t)(kk + 32) * 3072, kl1);
    GLOAD16(vg0 + kk, vl0);
    GLOAD16(vg0 + (size_t)32 * SEQ + kk, vl1);
    __syncthreads();                          // drains vmcnt for all waves

    // ---- QK^T: S[16 q][64 kv] ----
    short8 kf[4][2];
#pragma unroll
    for (int kb = 0; kb < 4; ++kb)
#pragma unroll
      for (int kc = 0; kc < 2; ++kc)
        kf[kb][kc] = *(const short8*)(Ks + (kb * 16 + lr) * 64 +
                                      (((kc * 4 + lg) ^ sw) * 8));
    f32x4 s[4];
#pragma unroll
    for (int kb = 0; kb < 4; ++kb) s[kb] = splat4(0.0f);
    __builtin_amdgcn_s_setprio(1);
#pragma unroll
    for (int kb = 0; kb < 4; ++kb) {
      s[kb] = __builtin_amdgcn_mfma_f32_16x16x32_bf16(qf[0], kf[kb][0], s[kb], 0, 0, 0);
      s[kb] = __builtin_amdgcn_mfma_f32_16x16x32_bf16(qf[1], kf[kb][1], s[kb], 0, 0, 0);
    }
    __builtin_amdgcn_s_setprio(0);

    // ---- scale (log2 domain) + causal mask ----
    const bool nm = (kk + 64 > wq0);
#pragma unroll
    for (int kb = 0; kb < 4; ++kb)
#pragma unroll
      for (int r = 0; r < 4; ++r) {
        float v = s[kb][r] * SC;
        if (nm) {
          const int q = wq0 + lg * 4 + r;
          if (kk + kb * 16 + lr > q) v = -INFINITY;
        }
        s[kb][r] = v;
      }

    // ---- online softmax (exp2 domain) ----
    f32x4 mx;
#pragma unroll
    for (int r = 0; r < 4; ++r)
      mx[r] = fmaxf(fmaxf(s[0][r], s[1][r]), fmaxf(s[2][r], s[3][r]));
#pragma unroll
    for (int msk = 1; msk < 16; msk <<= 1)
#pragma unroll
      for (int r = 0; r < 4; ++r)
        mx[r] = fmaxf(mx[r], __shfl_xor(mx[r], msk));
    f32x4 mnew, corr;
#pragma unroll
    for (int r = 0; r < 4; ++r) {
      mnew[r] = fmaxf(m_i[r], mx[r]);
      corr[r] = exp2f(m_i[r] - mnew[r]);
    }
#pragma unroll
    for (int kb = 0; kb < 4; ++kb)
#pragma unroll
      for (int r = 0; r < 4; ++r)
        s[kb][r] = exp2f(s[kb][r] - mnew[r]);
    f32x4 ps;
#pragma unroll
    for (int r = 0; r < 4; ++r)
      ps[r] = (s[0][r] + s[1][r]) + (s[2][r] + s[3][r]);
#pragma unroll
    for (int msk = 1; msk < 16; msk <<= 1)
#pragma unroll
      for (int r = 0; r < 4; ++r)
        ps[r] += __shfl_xor(ps[r], msk);
#pragma unroll
    for (int r = 0; r < 4; ++r) {
      l_i[r] = l_i[r] * corr[r] + ps[r];
      m_i[r] = mnew[r];
    }
#pragma unroll
    for (int n = 0; n < 4; ++n)
#pragma unroll
      for (int r = 0; r < 4; ++r) oacc[n][r] *= corr[r];

    // ---- P -> LDS (C-layout -> A-layout) ----
#pragma unroll
    for (int kb = 0; kb < 4; ++kb)
#pragma unroll
      for (int r = 0; r < 4; ++r)
        psw[(lg * 4 + r) * 72 + kb * 16 + lr] = f2bf(s[kb][r]);

    // ---- PV: O += P[16q][64kv] @ V^T[64kv][64d] ----
    short8 pf[2], vf[4][2];
#pragma unroll
    for (int kc = 0; kc < 2; ++kc)
      pf[kc] = *(const short8*)(psw + lr * 72 + kc * 32 + lg * 8);
#pragma unroll
    for (int n = 0; n < 4; ++n)
#pragma unroll
      for (int kc = 0; kc < 2; ++kc)
        vf[n][kc] = *(const short8*)(Vs + (n * 16 + lr) * 64 +
                                     (((kc * 4 + lg) ^ sw) * 8));
    __builtin_amdgcn_s_setprio(1);
#pragma unroll
    for (int n = 0; n < 4; ++n) {
      oacc[n] = __builtin_amdgcn_mfma_f32_16x16x32_bf16(pf[0], vf[n][0], oacc[n], 0, 0, 0);
      oacc[n] = __builtin_amdgcn_mfma_f32_16x16x32_bf16(pf[1], vf[n][1], oacc[n], 0, 0, 0);
    }
    __builtin_amdgcn_s_setprio(0);
  }

  // ---- write O ----
  f32x4 linv;
#pragma unroll
  for (int r = 0; r < 4; ++r) linv[r] = 1.0f / l_i[r];
#pragma unroll
  for (int n = 0; n < 4; ++n)
#pragma unroll
    for (int r = 0; r < 4; ++r)
      out[(size_t)(bb * SEQ + wq0 + lg * 4 + r) * BDIM + h * HDIM + n * 16 + lr]
          = f2bf(oacc[n][r] * linv[r]);
}

// ---------------- launch ------------------------------------------------------
extern "C" void kernel_launch(void* const* d_in, const int* in_sizes, int n_in,
                              void* d_out, int out_size, void* d_ws, size_t ws_size,
                              hipStream_t stream) {
  const float* x      = (const float*)d_in[0];
  const float* ln1_g  = (const float*)d_in[1];
  const float* ln1_b  = (const float*)d_in[2];
  const float* w_qkv  = (const float*)d_in[3];
  const float* b_qkv  = (const float*)d_in[4];
  const float* w_proj = (const float*)d_in[5];
  const float* b_proj = (const float*)d_in[6];
  const float* ln2_g  = (const float*)d_in[7];
  const float* ln2_b  = (const float*)d_in[8];
  const float* w_fc1  = (const float*)d_in[9];
  const float* b_fc1  = (const float*)d_in[10];
  const float* w_fc2  = (const float*)d_in[11];
  const float* b_fc2  = (const float*)d_in[12];
  float* out = (float*)d_out;

  char* ws = (char*)d_ws;
  unsigned short* wqkvT  = (unsigned short*)(ws + 0);         //  6 MB [3072][1024]
  unsigned short* wprojT = (unsigned short*)(ws + 6291456);   //  2 MB [1024][1024]
  unsigned short* wfc1T  = (unsigned short*)(ws + 8388608);   //  8 MB [4096][1024]
  unsigned short* wfc2T  = (unsigned short*)(ws + 16777216);  //  8 MB [1024][4096]
  unsigned short* hbuf   = (unsigned short*)(ws + 25165824);  //  8 MB [4096][1024] / vT [2][16][64][2048]
  float*          x2     = (float*)         (ws + 33554432);  // 16 MB [4096][1024]
  unsigned short* qkvb   = (unsigned short*)(ws + 50331648);  // 24 MB [4096][3072]
  unsigned short* attnb  = (unsigned short*)(ws + 75497472);  //  8 MB [4096][1024]
  unsigned short* fc1b   = (unsigned short*)(ws + 50331648);  // 32 MB [4096][4096] (reuse)

  tcvt_all<<<12288, 256, 0, stream>>>(w_qkv, w_proj, w_fc1, w_fc2,
                                      wqkvT, wprojT, wfc1T, wfc2T);

  ln_kernel<<<MROWS, 256, 0, stream>>>(x, ln1_g, ln1_b, hbuf);
  gemm_bt<0><<<dim3(3072 / 128, MROWS / 128), 256, 0, stream>>>(hbuf, wqkvT, b_qkv, nullptr, qkvb, MROWS, 3072, 1024);
  vtr_kernel<<<dim3(HDIM / 32, SEQ / 32, NB * NH), 256, 0, stream>>>(qkvb, hbuf);
  attn_kernel<<<dim3(SEQ / 64, NH, NB), 256, 0, stream>>>(qkvb, hbuf, attnb);
  gemm_bt_n64<<<dim3(1024 / 64, MROWS / 128), 256, 0, stream>>>(attnb, wprojT, b_proj, x, x2, MROWS, 1024, 1024);

  ln_kernel<<<MROWS, 256, 0, stream>>>(x2, ln2_g, ln2_b, hbuf);
  gemm_bt<2><<<dim3(4096 / 128, MROWS / 128), 256, 0, stream>>>(hbuf, wfc1T, b_fc1, nullptr, fc1b, MROWS, FFDIM, 1024);
  gemm_bt_n64<<<dim3(1024 / 64, MROWS / 128), 256, 0, stream>>>(fc1b, wfc2T, b_fc2, x2, out, MROWS, 1024, FFDIM);
}